// Round 3
// baseline (24.974 us; speedup 1.0000x reference)
//
#include <hip/hip_runtime.h>

// SoftHistogram: x[B=64, N=1000, F=256] fp32 -> out[B, F*K=2048] fp32
// out[b, f*8+k] = mean_n relu(1 - 16*|x[b,n,f] - (k+0.5)/8|)
// With u = 8x - 0.5:  y_k = relu(1 - 2*|u - k|).
//
// R3: fully-contiguous streaming. One wave-load = one whole 1-KB row
// (lane l -> float4 at f=4l). Blocks = (b, n-chunk of 125 rows): 512 blocks
// x 512 threads, each streams a contiguous 125-KB range. Cross-chunk reduce
// via d_ws + tiny phase-2 kernel (deterministic, no atomics).

#define PROCESS(v)                                                        \
    {                                                                     \
        const float xs[4] = {(v).x, (v).y, (v).z, (v).w};                 \
        _Pragma("unroll")                                                 \
        for (int i = 0; i < 4; ++i) {                                     \
            const float u = fmaf(xs[i], 8.0f, -0.5f);                     \
            _Pragma("unroll")                                             \
            for (int k = 0; k < 8; ++k) {                                 \
                const float y = fmaf(-2.0f, fabsf(u - (float)k), 1.0f);   \
                acc[i][k] += fmaxf(y, 0.0f);                              \
            }                                                             \
        }                                                                 \
    }

__global__ __launch_bounds__(512) void softhist_phase1(const float* __restrict__ x,
                                                       float* __restrict__ ws) {
    constexpr int N = 1000, F = 256, K = 8;
    constexpr int CH = 8;               // n-chunks per batch row
    constexpr int RC = N / CH;          // 125 rows per chunk

    const int bid = blockIdx.x;
    const int b  = bid >> 3;
    const int ch = bid & 7;
    const int t  = threadIdx.x;
    const int w  = t >> 6;              // wave 0..7
    const int l  = t & 63;              // lane

    float acc[4][K];
#pragma unroll
    for (int i = 0; i < 4; ++i)
#pragma unroll
        for (int k = 0; k < K; ++k) acc[i][k] = 0.0f;

    // lane l owns features 4l..4l+3; wave w handles rows w, w+8, ... of chunk
    const float* base = x + ((size_t)b * N + (size_t)ch * RC) * F + l * 4;

    int n = w;
    for (; n + 8 < RC; n += 16) {
        const float4 v0 = *reinterpret_cast<const float4*>(base + (size_t)n * F);
        const float4 v1 = *reinterpret_cast<const float4*>(base + (size_t)(n + 8) * F);
        PROCESS(v0);
        PROCESS(v1);
    }
    if (n < RC) {
        const float4 v = *reinterpret_cast<const float4*>(base + (size_t)n * F);
        PROCESS(v);
    }

    // Cross-wave reduce. part[w][l][33]: write banks (l+j)%32 -> 2-way (free).
    __shared__ float part[CH * 64 * 33];   // 67.6 KB
    float* my = &part[(w * 64 + l) * 33];
#pragma unroll
    for (int i = 0; i < 4; ++i)
#pragma unroll
        for (int k = 0; k < K; ++k) my[i * 8 + k] = acc[i][k];
    __syncthreads();

    // 2048 partial cols per block; thread t reduces cols t, t+512, t+1024, t+1536
    float* dst = ws + (size_t)bid * 2048;
#pragma unroll
    for (int m = 0; m < 4; ++m) {
        const int c  = t + 512 * m;
        const int lp = c >> 5;          // source lane
        const int j  = c & 31;          // i*8+k within lane
        float s = 0.0f;
#pragma unroll
        for (int ww = 0; ww < 8; ++ww) s += part[(ww * 64 + lp) * 33 + j];
        dst[c] = s;
    }
}

__global__ __launch_bounds__(256) void softhist_phase2(const float* __restrict__ ws,
                                                       float* __restrict__ out) {
    const int idx = blockIdx.x * 256 + threadIdx.x;   // 0..131071
    const int b = idx >> 11;
    const int c = idx & 2047;
    float s = 0.0f;
#pragma unroll
    for (int ch = 0; ch < 8; ++ch)
        s += ws[((size_t)(b * 8 + ch) << 11) + c];
    out[idx] = s * (1.0f / 1000.0f);
}

// ---- fallback (R2 kernel) if ws is too small ----
__global__ __launch_bounds__(512) void softhist_mono(const float* __restrict__ x,
                                                     float* __restrict__ out) {
    constexpr int N = 1000, F = 256, K = 8;
    constexpr int NS = 64, LSTR = 257;
    const int bid = blockIdx.x;
    const int b = bid >> 3, f0 = (bid & 7) * 32;
    const int t = threadIdx.x;
    const int fl8 = t & 7, nsub = t >> 3;

    float acc[4][K];
#pragma unroll
    for (int i = 0; i < 4; ++i)
#pragma unroll
        for (int k = 0; k < K; ++k) acc[i][k] = 0.0f;

    const float* base = x + (size_t)b * N * F + f0 + fl8 * 4;
    int n = nsub;
    for (; n + NS < N; n += 2 * NS) {
        const float4 v0 = *reinterpret_cast<const float4*>(base + (size_t)n * F);
        const float4 v1 = *reinterpret_cast<const float4*>(base + (size_t)(n + NS) * F);
        PROCESS(v0);
        PROCESS(v1);
    }
    if (n < N) {
        const float4 v = *reinterpret_cast<const float4*>(base + (size_t)n * F);
        PROCESS(v);
    }
    __shared__ float part[NS * LSTR];
#pragma unroll
    for (int i = 0; i < 4; ++i)
#pragma unroll
        for (int k = 0; k < K; ++k)
            part[nsub * LSTR + fl8 * 32 + i * 8 + k] = acc[i][k];
    __syncthreads();
    if (t < 256) {
        float s = 0.0f;
#pragma unroll
        for (int ns = 0; ns < NS; ++ns) s += part[ns * LSTR + t];
        out[(size_t)b * (F * K) + f0 * K + t] = s * (1.0f / (float)N);
    }
}

extern "C" void kernel_launch(void* const* d_in, const int* in_sizes, int n_in,
                              void* d_out, int out_size, void* d_ws, size_t ws_size,
                              hipStream_t stream) {
    const float* x = (const float*)d_in[0];
    float* out = (float*)d_out;
    const size_t ws_needed = (size_t)512 * 2048 * sizeof(float);  // 4 MB
    if (ws_size >= ws_needed) {
        float* ws = (float*)d_ws;
        softhist_phase1<<<dim3(512), dim3(512), 0, stream>>>(x, ws);
        softhist_phase2<<<dim3(512), dim3(256), 0, stream>>>(ws, out);
    } else {
        softhist_mono<<<dim3(512), dim3(512), 0, stream>>>(x, out);
    }
}

// Round 4
// 20.173 us; speedup vs baseline: 1.2380x; 1.2380x over previous
//
#include <hip/hip_runtime.h>

// SoftHistogram: x[B=64, N=1000, F=256] fp32 -> out[B, F*K=2048] fp32
// out[b, f*8+k] = mean_n relu(1 - 16*|x[b,n,f] - (k+0.5)/8|)
// R4: (a) max occupancy: 1024-thr blocks, grid 512 -> 2 blocks/CU = 32 waves/CU
//     (8/SIMD), double R1-R3's 4/SIMD.
//     (b) med3 inner loop: p = 16x-1; y_k = med3(0, (2k+1)-p, -(a_{k-1}))
//     -> 3 VALU ops per bin (was 4), 26/element (was 33).
//     (c) endgame: __shfl_xor(32) pre-reduce (128->64 rows), LDS layout
//     row*264 + fl8*33 + j (write: 32 distinct banks; read: conflict-free).

__global__ __launch_bounds__(1024) void softhist_kernel(const float* __restrict__ x,
                                                        float* __restrict__ out) {
    constexpr int N = 1000, F = 256, K = 8;
    constexpr int FG = 32;              // features per block
    constexpr int NSTR = 128;           // n stride (128 n-subgroups)

    __shared__ float part[64 * 264];    // 64 groups x (8 fl8-slots x 33 floats)

    const int bid = blockIdx.x;
    const int b   = bid >> 3;
    const int f0  = (bid & 7) * FG;
    const int t   = threadIdx.x;
    const int fl8  = t & 7;             // which float4 within the 32-f slice
    const int nsub = t >> 3;            // 0..127, n stride 128
    const int w    = t >> 6;            // wave 0..15
    const int l    = t & 63;            // lane

    float acc[4][K];
#pragma unroll
    for (int i = 0; i < 4; ++i)
#pragma unroll
        for (int k = 0; k < K; ++k) acc[i][k] = 0.0f;

    const float* base = x + (size_t)b * N * F + f0 + fl8 * 4;

    // y_k = relu(1-2|u-k|), u = 8x-0.5.  With p = 2u = 16x-1:
    //   a_k = (2k+1)-p, b_k = p-(2k-1) = -a_{k-1}, a_{-1} = -1-p
    //   y_k = max(0, min(a_k, b_k)) = med3(0, a_k, b_k)   [a_k + b_k = 2]
#define PROC(v)                                                              \
    {                                                                        \
        const float xs[4] = {(v).x, (v).y, (v).z, (v).w};                    \
        _Pragma("unroll")                                                    \
        for (int i = 0; i < 4; ++i) {                                        \
            const float p = fmaf(xs[i], 16.0f, -1.0f);                       \
            float aprev = -1.0f - p;                                         \
            _Pragma("unroll")                                                \
            for (int k = 0; k < K; ++k) {                                    \
                const float a = (float)(2 * k + 1) - p;                      \
                acc[i][k] += __builtin_amdgcn_fmed3f(0.0f, a, -aprev);       \
                aprev = a;                                                   \
            }                                                                \
        }                                                                    \
    }

    int n = nsub;
    for (; n + NSTR < N; n += 2 * NSTR) {
        const float4 v0 = *reinterpret_cast<const float4*>(base + (size_t)n * F);
        const float4 v1 = *reinterpret_cast<const float4*>(base + (size_t)(n + NSTR) * F);
        PROC(v0);
        PROC(v1);
    }
    if (n < N) {   // wave-uniform: 104 = 13*8, waves 13..15 take this with 7 rows done
        const float4 v = *reinterpret_cast<const float4*>(base + (size_t)n * F);
        PROC(v);
    }
#undef PROC

    // Pre-reduce across lane bit 5 (nsub partner +4): 128 -> 64 partial rows.
#pragma unroll
    for (int i = 0; i < 4; ++i)
#pragma unroll
        for (int k = 0; k < K; ++k)
            acc[i][k] += __shfl_xor(acc[i][k], 32, 64);

    if (l < 32) {
        const int g = w * 4 + (l >> 3);          // group 0..63
        float* dst = &part[g * 264 + fl8 * 33];  // banks: 8*(g&3)+fl8 -> all 32 distinct
#pragma unroll
        for (int i = 0; i < 4; ++i)
#pragma unroll
            for (int k = 0; k < K; ++k) dst[i * 8 + k] = acc[i][k];
    }
    __syncthreads();

    if (t < FG * K) {  // 256 output columns per block
        const int off = (t >> 5) * 33 + (t & 31);
        float s = 0.0f;
#pragma unroll
        for (int g = 0; g < 64; ++g) s += part[g * 264 + off];
        out[(size_t)b * (F * K) + f0 * K + t] = s * (1.0f / (float)N);
    }
}

extern "C" void kernel_launch(void* const* d_in, const int* in_sizes, int n_in,
                              void* d_out, int out_size, void* d_ws, size_t ws_size,
                              hipStream_t stream) {
    const float* x = (const float*)d_in[0];
    float* out = (float*)d_out;
    // 64 b x 8 f-slices -> 512 blocks of 1024 threads (2 blocks/CU, 32 waves/CU)
    softhist_kernel<<<dim3(64 * 8), dim3(1024), 0, stream>>>(x, out);
}

// Round 5
// 19.108 us; speedup vs baseline: 1.3070x; 1.0557x over previous
//
#include <hip/hip_runtime.h>

// SoftHistogram: x[B=64, N=1000, F=256] fp32 -> out[B, F*K=2048] fp32
// out[b, f*8+k] = mean_n relu(1 - 16*|x[b,n,f] - (k+0.5)/8|)
//
// R5: nearest-bin formulation. Triangles have half-width 0.5 at unit spacing
// (u = 8x-0.5): at most ONE bin is nonzero per element, k* = round(u).
// Per element: 8 VALU + exec-masked LDS RMW into a wave-private histogram
// (k-major [k][256f]; lane<->feature => addresses lane-unique; deterministic,
// no atomics). Contiguous 1-KB row loads (lane l -> float4 at f=4l), n-loop
// unrolled x2. 512-thr blocks, 64 KB LDS -> 2 blocks/CU. Grid: 64 b x 8
// n-chunks = 512 blocks. Cross-chunk reduce via 4 MB ws + phase2.

constexpr int N = 1000, F = 256, K = 8;
constexpr int CH = 8;              // n-chunks per batch row
constexpr int RC = N / CH;         // 125 rows per chunk
constexpr int WPB = 8;             // waves per block

__global__ __launch_bounds__(512) void softhist_phase1(const float* __restrict__ x,
                                                       float* __restrict__ ws) {
    __shared__ float hist[WPB * K * F];   // 8 waves x [k][f] = 64 KB exactly

    const int bid = blockIdx.x;
    const int b  = bid >> 3;
    const int ch = bid & 7;
    const int t  = threadIdx.x;
    const int w  = t >> 6;             // wave 0..7
    const int l  = t & 63;             // lane

    // zero the histograms (8 float4 stores per thread, conflict-free)
#pragma unroll
    for (int z = 0; z < 8; ++z)
        *reinterpret_cast<float4*>(&hist[(z * 512 + t) * 4]) = float4{0.f, 0.f, 0.f, 0.f};
    __syncthreads();

    float* wh = &hist[w * (K * F)];
    const float* base = x + ((size_t)b * N + (size_t)ch * RC) * F + l * 4;

    auto proc = [&](const float4 v) {
        const float xs[4] = {v.x, v.y, v.z, v.w};
#pragma unroll
        for (int i = 0; i < 4; ++i) {
            const float h  = fmaf(xs[i], 8.0f, -0.5f);          // u = 8x - 0.5
            const float kf = __builtin_rintf(h);                 // v_rndne
            const float kc = __builtin_amdgcn_fmed3f(kf, 0.0f, 7.0f);
            const float y  = fmaf(-2.0f, fabsf(h - kc), 1.0f);   // 1 - 2|u-k*|
            if (y > 0.0f) {                                      // ~34% of lanes
                const int ki = (int)kc;
                wh[ki * F + 4 * l + i] += y;   // lane-unique addr: f = 4l+i
            }
        }
    };

    int n = w;
    for (; n + WPB < RC; n += 2 * WPB) {
        const float4 v0 = *reinterpret_cast<const float4*>(base + (size_t)n * F);
        const float4 v1 = *reinterpret_cast<const float4*>(base + (size_t)(n + WPB) * F);
        proc(v0);
        proc(v1);
    }
    if (n < RC)
        proc(*reinterpret_cast<const float4*>(base + (size_t)n * F));
    __syncthreads();

    // Reduce 8 wave-hists -> 2048 block partials, written as c = f*8+k so
    // phase2 is fully linear. Thread u: f = u&255, k = 4*(u>>8)+j.
    // LDS reads: consecutive lanes -> consecutive f -> 32 distinct banks.
    const int f  = t & 255;
    const int kb = (t >> 8) * 4;
    float4 r;
    float* rr = &r.x;
#pragma unroll
    for (int j = 0; j < 4; ++j) {
        const int off = (kb + j) * F + f;
        float s = 0.0f;
#pragma unroll
        for (int ww = 0; ww < WPB; ++ww) s += hist[ww * (K * F) + off];
        rr[j] = s;
    }
    *reinterpret_cast<float4*>(ws + (size_t)bid * 2048 + f * 8 + kb) = r;
}

__global__ __launch_bounds__(256) void softhist_phase2(const float* __restrict__ ws,
                                                       float* __restrict__ out) {
    const int idx = blockIdx.x * 256 + threadIdx.x;   // 0..131071
    const int b = idx >> 11;
    const int c = idx & 2047;
    float s = 0.0f;
#pragma unroll
    for (int ch = 0; ch < CH; ++ch)
        s += ws[((size_t)(b * CH + ch) << 11) + c];
    out[idx] = s * (1.0f / (float)N);
}

// ---- fallback (R4 kernel) if ws is unexpectedly small ----
__global__ __launch_bounds__(1024) void softhist_mono(const float* __restrict__ x,
                                                      float* __restrict__ out) {
    constexpr int FG = 32, NSTR = 128;
    __shared__ float part[64 * 264];
    const int bid = blockIdx.x;
    const int b = bid >> 3, f0 = (bid & 7) * FG;
    const int t = threadIdx.x;
    const int fl8 = t & 7, nsub = t >> 3;
    const int w = t >> 6, l = t & 63;

    float acc[4][K];
#pragma unroll
    for (int i = 0; i < 4; ++i)
#pragma unroll
        for (int k = 0; k < K; ++k) acc[i][k] = 0.0f;

    const float* base = x + (size_t)b * N * F + f0 + fl8 * 4;
#define PROC4(v)                                                             \
    {                                                                        \
        const float xs[4] = {(v).x, (v).y, (v).z, (v).w};                    \
        _Pragma("unroll")                                                    \
        for (int i = 0; i < 4; ++i) {                                        \
            const float p = fmaf(xs[i], 16.0f, -1.0f);                       \
            float aprev = -1.0f - p;                                         \
            _Pragma("unroll")                                                \
            for (int k = 0; k < K; ++k) {                                    \
                const float a = (float)(2 * k + 1) - p;                      \
                acc[i][k] += __builtin_amdgcn_fmed3f(0.0f, a, -aprev);       \
                aprev = a;                                                   \
            }                                                                \
        }                                                                    \
    }
    int n = nsub;
    for (; n + NSTR < N; n += 2 * NSTR) {
        const float4 v0 = *reinterpret_cast<const float4*>(base + (size_t)n * F);
        const float4 v1 = *reinterpret_cast<const float4*>(base + (size_t)(n + NSTR) * F);
        PROC4(v0);
        PROC4(v1);
    }
    if (n < N) {
        const float4 v = *reinterpret_cast<const float4*>(base + (size_t)n * F);
        PROC4(v);
    }
#undef PROC4
#pragma unroll
    for (int i = 0; i < 4; ++i)
#pragma unroll
        for (int k = 0; k < K; ++k) acc[i][k] += __shfl_xor(acc[i][k], 32, 64);
    if (l < 32) {
        const int g = w * 4 + (l >> 3);
        float* dst = &part[g * 264 + fl8 * 33];
#pragma unroll
        for (int i = 0; i < 4; ++i)
#pragma unroll
            for (int k = 0; k < K; ++k) dst[i * 8 + k] = acc[i][k];
    }
    __syncthreads();
    if (t < FG * K) {
        const int off = (t >> 5) * 33 + (t & 31);
        float s = 0.0f;
#pragma unroll
        for (int g = 0; g < 64; ++g) s += part[g * 264 + off];
        out[(size_t)b * (F * K) + f0 * K + t] = s * (1.0f / (float)N);
    }
}

extern "C" void kernel_launch(void* const* d_in, const int* in_sizes, int n_in,
                              void* d_out, int out_size, void* d_ws, size_t ws_size,
                              hipStream_t stream) {
    const float* x = (const float*)d_in[0];
    float* out = (float*)d_out;
    const size_t ws_needed = (size_t)512 * 2048 * sizeof(float);  // 4 MB
    if (ws_size >= ws_needed) {
        float* ws = (float*)d_ws;
        softhist_phase1<<<dim3(512), dim3(512), 0, stream>>>(x, ws);
        softhist_phase2<<<dim3(512), dim3(256), 0, stream>>>(ws, out);
    } else {
        softhist_mono<<<dim3(512), dim3(1024), 0, stream>>>(x, out);
    }
}